// Round 8
// baseline (100.223 us; speedup 1.0000x reference)
//
#include <hip/hip_runtime.h>
#include <hip/hip_bf16.h>
#include <stdint.h>

#define B_ 256
#define D_ 10
#define P_ 1152
#define I_ 16
#define J_ 8

#define NPT 18            // s_part slices (p-groups of 64)
#define SLOTS (P_ * 8)    // u32 slots per (b,d), layout: slot = p*8 + c

typedef float f32x4 __attribute__((ext_vector_type(4)));

// packed bf16 pair via HW cvt (RNE): low16 = bf16(lo), high16 = bf16(hi)
__device__ inline uint32_t pk_bf16(float lo, float hi) {
    uint32_t r;
    asm("v_cvt_pk_bf16_f32 %0, %1, %2" : "=v"(r) : "v"(lo), "v"(hi));
    return r;
}

// Block = (d, pg of 64 p, bc of 64 b), 512 threads = 8 waves:
// wave w: hp = w>>2 (p-half), wb = w&3 (b-phase). Lane: p_l = (l>>1), ih = l&1.
// W[d, p, i-half] -> 16 f32x4 registers, pinned by volatile asm so the
// allocator can NOT rematerialize the loads in-loop (r6/r7: VGPR=48, FETCH
// 48.5 MB, latency-bound because W was re-loaded 16x from L2).
// Loop over 16 b: 2 x-loads + 64 FMA + 4 cvt_pk + 1 uint4 store (wave: 1KB
// contiguous) + butterfly s0-reduce (9 shfl, no barriers).
__global__ __launch_bounds__(512, 4) void k_uhat(
    const float* __restrict__ x, const float* __restrict__ W,
    uint32_t* __restrict__ uhat, float* __restrict__ s_part)
{
    const int bid = blockIdx.x;
    const int d = bid % D_;
    const int pb = bid / D_;        // 0..71
    const int bc = pb & 3;
    const int pg = pb >> 2;         // 0..17

    const int tid = threadIdx.x;
    const int l = tid & 63;
    const int w = tid >> 6;
    const int hp = w >> 2;
    const int wb = w & 3;
    const int ih = l & 1;           // i-half: i = ih*8 .. ih*8+7
    const int p_l = l >> 1;         // 0..31
    const int p = pg * 64 + hp * 32 + p_l;

    __shared__ float lsum[2][4][16][16];   // [hp][wb][it][i], 8 KB

    // W fragment -> 16 f32x4 registers (256 B contiguous per lane), then pin.
    const f32x4* wg = (const f32x4*)W + (size_t)(d * P_ + p) * 32 + ih * 16;
    f32x4 wf[16];
    #pragma unroll
    for (int q = 0; q < 16; ++q) wf[q] = wg[q];
    #pragma unroll
    for (int q = 0; q < 16; ++q) asm volatile("" : "+v"(wf[q]));

    const int b0 = bc * 64 + wb;
    const float4* xg = (const float4*)x + ((size_t)b0 * P_ + p) * 2;
    uint4* ug = (uint4*)uhat + ((size_t)(b0 * D_ + d) * P_ + p) * 2 + ih;

    float4 xA = xg[0], xB = xg[1];
    for (int it = 0; it < 16; ++it) {
        // prefetch next b
        float4 nA, nB;
        if (it < 15) {
            const float4* xn = xg + 4 * (P_ * 2);
            nA = xn[0]; nB = xn[1];
            xg = xn;
        }

        float u[8];
        #pragma unroll
        for (int i = 0; i < 8; ++i) {
            const f32x4 wA = wf[i * 2], wB = wf[i * 2 + 1];
            u[i] = wA[0]*xA.x + wA[1]*xA.y + wA[2]*xA.z + wA[3]*xA.w
                 + wB[0]*xB.x + wB[1]*xB.y + wB[2]*xB.z + wB[3]*xB.w;
        }

        uint4 st;
        st.x = pk_bf16(u[0], u[1]);
        st.y = pk_bf16(u[2], u[3]);
        st.z = pk_bf16(u[4], u[5]);
        st.w = pk_bf16(u[6], u[7]);
        *ug = st;
        ug += 4 * (size_t)(D_ * P_ * 2);

        // butterfly: sum u[8] over the 32 p_l lanes, splitting values each round
        const int s1 = (l >> 1) & 1;
        float k0 = s1 ? u[4] : u[0];
        float k1 = s1 ? u[5] : u[1];
        float k2 = s1 ? u[6] : u[2];
        float k3 = s1 ? u[7] : u[3];
        float g0 = s1 ? u[0] : u[4];
        float g1 = s1 ? u[1] : u[5];
        float g2 = s1 ? u[2] : u[6];
        float g3 = s1 ? u[3] : u[7];
        k0 += __shfl_xor(g0, 2);
        k1 += __shfl_xor(g1, 2);
        k2 += __shfl_xor(g2, 2);
        k3 += __shfl_xor(g3, 2);
        const int s2 = (l >> 2) & 1;
        float m0 = s2 ? k2 : k0;
        float m1 = s2 ? k3 : k1;
        float h0 = s2 ? k0 : k2;
        float h1 = s2 ? k1 : k3;
        m0 += __shfl_xor(h0, 4);
        m1 += __shfl_xor(h1, 4);
        const int s3 = (l >> 3) & 1;
        float v  = s3 ? m1 : m0;
        float gv = s3 ? m0 : m1;
        v += __shfl_xor(gv, 8);
        v += __shfl_xor(v, 16);
        v += __shfl_xor(v, 32);
        // lane l<16 holds total for i = 8*ih + 4*s1 + 2*s2 + s3
        if (l < 16) {
            const int iof = ih * 8 + s1 * 4 + s2 * 2 + s3;
            lsum[hp][wb][it][iof] = v;
        }

        xA = nA; xB = nB;
    }
    __syncthreads();

    // combine the two p-halves, write s_part slice
    for (int k = tid; k < 1024; k += 512) {
        const int i = k & 15;
        const int it = (k >> 4) & 15;
        const int wb2 = k >> 8;
        const float v = lsum[0][wb2][it][i] + lsum[1][wb2][it][i];
        const int b = bc * 64 + it * 4 + wb2;
        s_part[(size_t)pg * (B_ * D_ * I_) + (size_t)b * (D_ * I_) + d * 16 + i] = v;
    }
}

// Sum the 18 p-group partials -> s0 (x0.1), n2_0 = sum s0^2.
__global__ __launch_bounds__(256) void k_sred(const float* __restrict__ s_part,
                                              float* __restrict__ s, float* __restrict__ n2)
{
    const int gid = blockIdx.x * 256 + threadIdx.x;   // (b,d,i)
    float v = 0.f;
    #pragma unroll
    for (int pt = 0; pt < NPT; ++pt) v += s_part[(size_t)pt * (B_ * D_ * I_) + gid];
    v *= 0.1f;
    s[gid] = v;
    float v2 = v * v;
    #pragma unroll
    for (int st = 1; st < 64; st <<= 1) v2 += __shfl_xor(v2, st);
    __shared__ float r4[4];
    const int lane = threadIdx.x & 63, wave = threadIdx.x >> 6;
    if (lane == 0) r4[wave] = v2;
    __syncthreads();
    if (threadIdx.x == 0) atomicAdd(n2, r4[0] + r4[1] + r4[2] + r4[3]);
}

// Block per b. tls = g0*s0 (+ g1*s1 if rnd==2); logits = u_hat . tls;
// softmax over d; accumulate s_out, n2[rnd]. Wave reads 256B contiguous.
__global__ __launch_bounds__(1024) void k_route(
    const uint32_t* __restrict__ uhat,
    const float* __restrict__ s0, const float* __restrict__ s1,
    const float* __restrict__ n2v, int rnd,
    float* __restrict__ s_out)
{
    const int b = blockIdx.x;
    const int tid = threadIdx.x;

    __shared__ float tls[D_ * I_];
    __shared__ float sw[16][D_ * I_];
    __shared__ float n2l;

    if (tid < D_ * I_) {
        const float n20 = n2v[0];
        const float g0 = (n20 / (n20 + 1.f)) / (sqrtf(n20) + 1e-7f);
        float v = g0 * s0[(size_t)b * D_ * I_ + tid];
        if (rnd == 2) {
            const float n21 = n2v[1];
            const float g1 = (n21 / (n21 + 1.f)) / (sqrtf(n21) + 1e-7f);
            v += g1 * s1[(size_t)b * D_ * I_ + tid];
        }
        tls[tid] = v;
    }
    if (tid == 0) n2l = 0.f;
    __syncthreads();

    const int wv = tid >> 6;     // wave 0..15
    const int l = tid & 63;
    const int tb = l >> 3;       // team-in-wave 0..7
    const int tl = l & 7;        // i-pair
    const uint32_t* ubase = uhat + (size_t)b * D_ * SLOTS;

    float sacc[D_][2];
    #pragma unroll
    for (int d = 0; d < D_; ++d) { sacc[d][0] = 0.f; sacc[d][1] = 0.f; }

    for (int k = 0; k < 9; ++k) {
        const int p = k * 128 + wv * 8 + tb;
        const uint32_t* up = ubase + p * 8 + tl;   // plain [p][c] layout
        float u[D_][2];
        float beta[D_];
        #pragma unroll
        for (int d = 0; d < D_; ++d) {
            const uint32_t wq = up[(size_t)d * SLOTS];
            const float u0 = __uint_as_float(wq << 16);
            const float u1 = __uint_as_float(wq & 0xffff0000u);
            u[d][0] = u0; u[d][1] = u1;
            float bp = u0 * tls[d * I_ + 2 * tl] + u1 * tls[d * I_ + 2 * tl + 1];
            bp += __shfl_xor(bp, 1);
            bp += __shfl_xor(bp, 2);
            bp += __shfl_xor(bp, 4);
            beta[d] = bp;
        }
        float m = beta[0];
        #pragma unroll
        for (int d = 1; d < D_; ++d) m = fmaxf(m, beta[d]);
        float cc[D_]; float Z = 0.f;
        #pragma unroll
        for (int d = 0; d < D_; ++d) { cc[d] = __expf(beta[d] - m); Z += cc[d]; }
        const float rz = 1.f / Z;
        #pragma unroll
        for (int d = 0; d < D_; ++d) {
            const float cd = cc[d] * rz;
            sacc[d][0] += cd * u[d][0];
            sacc[d][1] += cd * u[d][1];
        }
    }

    #pragma unroll
    for (int st = 8; st < 64; st <<= 1) {
        #pragma unroll
        for (int d = 0; d < D_; ++d) {
            sacc[d][0] += __shfl_xor(sacc[d][0], st);
            sacc[d][1] += __shfl_xor(sacc[d][1], st);
        }
    }
    if (l < 8) {
        #pragma unroll
        for (int d = 0; d < D_; ++d) {
            sw[wv][d * I_ + 2 * tl]     = sacc[d][0];
            sw[wv][d * I_ + 2 * tl + 1] = sacc[d][1];
        }
    }
    __syncthreads();

    if (tid < D_ * I_) {
        float v = 0.f;
        #pragma unroll
        for (int w2 = 0; w2 < 16; ++w2) v += sw[w2][tid];
        s_out[(size_t)b * D_ * I_ + tid] = v;
        atomicAdd(&n2l, v * v);
    }
    __syncthreads();
    if (tid == 0) atomicAdd((float*)(n2v + rnd), n2l);
}

// Final in-place rescale: out *= g(n2_2)
__global__ void k_out(float* __restrict__ out, const float* __restrict__ n2p)
{
    const int i = blockIdx.x * 256 + threadIdx.x;
    const float n2 = *n2p;
    const float g = (n2 / (n2 + 1.f)) / (sqrtf(n2) + 1e-7f);
    out[i] *= g;
}

extern "C" void kernel_launch(void* const* d_in, const int* in_sizes, int n_in,
                              void* d_out, int out_size, void* d_ws, size_t ws_size,
                              hipStream_t stream)
{
    const float* x = (const float*)d_in[0];   // [256,1152,8]
    const float* W = (const float*)d_in[1];   // [10,1152,16,8]
    float* out = (float*)d_out;               // [256,10,16]

    char* ws = (char*)d_ws;
    uint32_t* uhat = (uint32_t*)ws;                              // bf16x2, 94,371,840 B
    const size_t uhat_bytes = (size_t)B_ * D_ * P_ * I_ * 2;
    float* s_part = (float*)(ws + uhat_bytes);                   // [18][B*D*I] = 2.95 MB
    float* s0 = s_part + (size_t)NPT * B_ * D_ * I_;             // [B*D*I]
    float* s1 = s0 + B_ * D_ * I_;                               // [B*D*I]
    float* n2 = s1 + B_ * D_ * I_;                               // [3]

    hipMemsetAsync(n2, 0, 3 * sizeof(float), stream);

    // r = 0: u_hat production + uniform-c (0.1) partial sums
    k_uhat<<<NPT * 4 * D_, 512, 0, stream>>>(x, W, uhat, s_part);
    k_sred<<<(B_ * D_ * I_) / 256, 256, 0, stream>>>(s_part, s0, n2 + 0);
    // r = 1: t = g0*s0
    k_route<<<B_, 1024, 0, stream>>>(uhat, s0, s1, n2, 1, s1);
    // r = 2: t = g0*s0 + g1*s1; raw s2 -> d_out
    k_route<<<B_, 1024, 0, stream>>>(uhat, s0, s1, n2, 2, out);
    // out = g2 * s2 (in place)
    k_out<<<(B_ * D_ * I_) / 256, 256, 0, stream>>>(out, n2 + 2);
}

// Round 9
// 98.315 us; speedup vs baseline: 1.0194x; 1.0194x over previous
//
#include <hip/hip_runtime.h>
#include <hip/hip_bf16.h>
#include <stdint.h>

#define B_ 256
#define D_ 10
#define P_ 1152
#define I_ 16
#define J_ 8

#define NPT 18            // s_part slices (p-groups of 64)
#define SLOTS (P_ * 8)    // u32 slots per (b,d), layout: slot = p*8 + c

typedef float f32x4 __attribute__((ext_vector_type(4)));

// packed bf16 pair via HW cvt (RNE): low16 = bf16(lo), high16 = bf16(hi)
__device__ inline uint32_t pk_bf16(float lo, float hi) {
    uint32_t r;
    asm("v_cvt_pk_bf16_f32 %0, %1, %2" : "=v"(r) : "v"(lo), "v"(hi));
    return r;
}

// Identical to round 8 EXCEPT the block-index decode: XCD-pinned families.
// bid = g + 8*(F9*10 + d): all 10 d-blocks of family (pg,bc) have bid%8 == g
// -> land on one XCD (round-robin heuristic) -> the family's x slice (128 KB)
// and W slices (2.9 MB over 9 families) stay L2-resident per XCD.
// r8 evidence: FETCH 48.5 MB = x re-reads from L3 (no pinning), not W remat
// (W sits in AGPRs; VGPR_Count=48 counts only arch VGPRs).
__global__ __launch_bounds__(512, 4) void k_uhat(
    const float* __restrict__ x, const float* __restrict__ W,
    uint32_t* __restrict__ uhat, float* __restrict__ s_part)
{
    const int bid = blockIdx.x;
    const int g = bid & 7;          // XCD
    const int r = bid >> 3;         // 0..89
    const int F9 = r / 10;          // 0..8 family-within-XCD
    const int d = r - F9 * 10;      // 0..9
    const int FI = g * 9 + F9;      // 0..71 family = (pg, bc)
    const int pg = FI % 18;
    const int bc = FI / 18;         // 0..3

    const int tid = threadIdx.x;
    const int l = tid & 63;
    const int w = tid >> 6;
    const int hp = w >> 2;
    const int wb = w & 3;
    const int ih = l & 1;           // i-half: i = ih*8 .. ih*8+7
    const int p_l = l >> 1;         // 0..31
    const int p = pg * 64 + hp * 32 + p_l;

    __shared__ float lsum[2][4][16][16];   // [hp][wb][it][i], 8 KB

    // W fragment -> 16 f32x4 registers (256 B contiguous per lane), then pin.
    const f32x4* wg = (const f32x4*)W + (size_t)(d * P_ + p) * 32 + ih * 16;
    f32x4 wf[16];
    #pragma unroll
    for (int q = 0; q < 16; ++q) wf[q] = wg[q];
    #pragma unroll
    for (int q = 0; q < 16; ++q) asm volatile("" : "+v"(wf[q]));

    const int b0 = bc * 64 + wb;
    const float4* xg = (const float4*)x + ((size_t)b0 * P_ + p) * 2;
    uint4* ug = (uint4*)uhat + ((size_t)(b0 * D_ + d) * P_ + p) * 2 + ih;

    float4 xA = xg[0], xB = xg[1];
    for (int it = 0; it < 16; ++it) {
        // prefetch next b
        float4 nA, nB;
        if (it < 15) {
            const float4* xn = xg + 4 * (P_ * 2);
            nA = xn[0]; nB = xn[1];
            xg = xn;
        }

        float u[8];
        #pragma unroll
        for (int i = 0; i < 8; ++i) {
            const f32x4 wA = wf[i * 2], wB = wf[i * 2 + 1];
            u[i] = wA[0]*xA.x + wA[1]*xA.y + wA[2]*xA.z + wA[3]*xA.w
                 + wB[0]*xB.x + wB[1]*xB.y + wB[2]*xB.z + wB[3]*xB.w;
        }

        uint4 st;
        st.x = pk_bf16(u[0], u[1]);
        st.y = pk_bf16(u[2], u[3]);
        st.z = pk_bf16(u[4], u[5]);
        st.w = pk_bf16(u[6], u[7]);
        *ug = st;
        ug += 4 * (size_t)(D_ * P_ * 2);

        // butterfly: sum u[8] over the 32 p_l lanes, splitting values each round
        const int s1 = (l >> 1) & 1;
        float k0 = s1 ? u[4] : u[0];
        float k1 = s1 ? u[5] : u[1];
        float k2 = s1 ? u[6] : u[2];
        float k3 = s1 ? u[7] : u[3];
        float g0 = s1 ? u[0] : u[4];
        float g1 = s1 ? u[1] : u[5];
        float g2 = s1 ? u[2] : u[6];
        float g3 = s1 ? u[3] : u[7];
        k0 += __shfl_xor(g0, 2);
        k1 += __shfl_xor(g1, 2);
        k2 += __shfl_xor(g2, 2);
        k3 += __shfl_xor(g3, 2);
        const int s2 = (l >> 2) & 1;
        float m0 = s2 ? k2 : k0;
        float m1 = s2 ? k3 : k1;
        float h0 = s2 ? k0 : k2;
        float h1 = s2 ? k1 : k3;
        m0 += __shfl_xor(h0, 4);
        m1 += __shfl_xor(h1, 4);
        const int s3 = (l >> 3) & 1;
        float v  = s3 ? m1 : m0;
        float gv = s3 ? m0 : m1;
        v += __shfl_xor(gv, 8);
        v += __shfl_xor(v, 16);
        v += __shfl_xor(v, 32);
        // lane l<16 holds total for i = 8*ih + 4*s1 + 2*s2 + s3
        if (l < 16) {
            const int iof = ih * 8 + s1 * 4 + s2 * 2 + s3;
            lsum[hp][wb][it][iof] = v;
        }

        xA = nA; xB = nB;
    }
    __syncthreads();

    // combine the two p-halves, write s_part slice
    for (int k = tid; k < 1024; k += 512) {
        const int i = k & 15;
        const int it = (k >> 4) & 15;
        const int wb2 = k >> 8;
        const float v = lsum[0][wb2][it][i] + lsum[1][wb2][it][i];
        const int b = bc * 64 + it * 4 + wb2;
        s_part[(size_t)pg * (B_ * D_ * I_) + (size_t)b * (D_ * I_) + d * 16 + i] = v;
    }
}

// Sum the 18 p-group partials -> s0 (x0.1), n2_0 = sum s0^2.
__global__ __launch_bounds__(256) void k_sred(const float* __restrict__ s_part,
                                              float* __restrict__ s, float* __restrict__ n2)
{
    const int gid = blockIdx.x * 256 + threadIdx.x;   // (b,d,i)
    float v = 0.f;
    #pragma unroll
    for (int pt = 0; pt < NPT; ++pt) v += s_part[(size_t)pt * (B_ * D_ * I_) + gid];
    v *= 0.1f;
    s[gid] = v;
    float v2 = v * v;
    #pragma unroll
    for (int st = 1; st < 64; st <<= 1) v2 += __shfl_xor(v2, st);
    __shared__ float r4[4];
    const int lane = threadIdx.x & 63, wave = threadIdx.x >> 6;
    if (lane == 0) r4[wave] = v2;
    __syncthreads();
    if (threadIdx.x == 0) atomicAdd(n2, r4[0] + r4[1] + r4[2] + r4[3]);
}

// Block per b. tls = g0*s0 (+ g1*s1 if rnd==2); logits = u_hat . tls;
// softmax over d; accumulate s_out, n2[rnd]. Wave reads 256B contiguous.
__global__ __launch_bounds__(1024) void k_route(
    const uint32_t* __restrict__ uhat,
    const float* __restrict__ s0, const float* __restrict__ s1,
    const float* __restrict__ n2v, int rnd,
    float* __restrict__ s_out)
{
    const int b = blockIdx.x;
    const int tid = threadIdx.x;

    __shared__ float tls[D_ * I_];
    __shared__ float sw[16][D_ * I_];
    __shared__ float n2l;

    if (tid < D_ * I_) {
        const float n20 = n2v[0];
        const float g0 = (n20 / (n20 + 1.f)) / (sqrtf(n20) + 1e-7f);
        float v = g0 * s0[(size_t)b * D_ * I_ + tid];
        if (rnd == 2) {
            const float n21 = n2v[1];
            const float g1 = (n21 / (n21 + 1.f)) / (sqrtf(n21) + 1e-7f);
            v += g1 * s1[(size_t)b * D_ * I_ + tid];
        }
        tls[tid] = v;
    }
    if (tid == 0) n2l = 0.f;
    __syncthreads();

    const int wv = tid >> 6;     // wave 0..15
    const int l = tid & 63;
    const int tb = l >> 3;       // team-in-wave 0..7
    const int tl = l & 7;        // i-pair
    const uint32_t* ubase = uhat + (size_t)b * D_ * SLOTS;

    float sacc[D_][2];
    #pragma unroll
    for (int d = 0; d < D_; ++d) { sacc[d][0] = 0.f; sacc[d][1] = 0.f; }

    for (int k = 0; k < 9; ++k) {
        const int p = k * 128 + wv * 8 + tb;
        const uint32_t* up = ubase + p * 8 + tl;   // plain [p][c] layout
        float u[D_][2];
        float beta[D_];
        #pragma unroll
        for (int d = 0; d < D_; ++d) {
            const uint32_t wq = up[(size_t)d * SLOTS];
            const float u0 = __uint_as_float(wq << 16);
            const float u1 = __uint_as_float(wq & 0xffff0000u);
            u[d][0] = u0; u[d][1] = u1;
            float bp = u0 * tls[d * I_ + 2 * tl] + u1 * tls[d * I_ + 2 * tl + 1];
            bp += __shfl_xor(bp, 1);
            bp += __shfl_xor(bp, 2);
            bp += __shfl_xor(bp, 4);
            beta[d] = bp;
        }
        float m = beta[0];
        #pragma unroll
        for (int d = 1; d < D_; ++d) m = fmaxf(m, beta[d]);
        float cc[D_]; float Z = 0.f;
        #pragma unroll
        for (int d = 0; d < D_; ++d) { cc[d] = __expf(beta[d] - m); Z += cc[d]; }
        const float rz = 1.f / Z;
        #pragma unroll
        for (int d = 0; d < D_; ++d) {
            const float cd = cc[d] * rz;
            sacc[d][0] += cd * u[d][0];
            sacc[d][1] += cd * u[d][1];
        }
    }

    #pragma unroll
    for (int st = 8; st < 64; st <<= 1) {
        #pragma unroll
        for (int d = 0; d < D_; ++d) {
            sacc[d][0] += __shfl_xor(sacc[d][0], st);
            sacc[d][1] += __shfl_xor(sacc[d][1], st);
        }
    }
    if (l < 8) {
        #pragma unroll
        for (int d = 0; d < D_; ++d) {
            sw[wv][d * I_ + 2 * tl]     = sacc[d][0];
            sw[wv][d * I_ + 2 * tl + 1] = sacc[d][1];
        }
    }
    __syncthreads();

    if (tid < D_ * I_) {
        float v = 0.f;
        #pragma unroll
        for (int w2 = 0; w2 < 16; ++w2) v += sw[w2][tid];
        s_out[(size_t)b * D_ * I_ + tid] = v;
        atomicAdd(&n2l, v * v);
    }
    __syncthreads();
    if (tid == 0) atomicAdd((float*)(n2v + rnd), n2l);
}

// Final in-place rescale: out *= g(n2_2)
__global__ void k_out(float* __restrict__ out, const float* __restrict__ n2p)
{
    const int i = blockIdx.x * 256 + threadIdx.x;
    const float n2 = *n2p;
    const float g = (n2 / (n2 + 1.f)) / (sqrtf(n2) + 1e-7f);
    out[i] *= g;
}

extern "C" void kernel_launch(void* const* d_in, const int* in_sizes, int n_in,
                              void* d_out, int out_size, void* d_ws, size_t ws_size,
                              hipStream_t stream)
{
    const float* x = (const float*)d_in[0];   // [256,1152,8]
    const float* W = (const float*)d_in[1];   // [10,1152,16,8]
    float* out = (float*)d_out;               // [256,10,16]

    char* ws = (char*)d_ws;
    uint32_t* uhat = (uint32_t*)ws;                              // bf16x2, 94,371,840 B
    const size_t uhat_bytes = (size_t)B_ * D_ * P_ * I_ * 2;
    float* s_part = (float*)(ws + uhat_bytes);                   // [18][B*D*I] = 2.95 MB
    float* s0 = s_part + (size_t)NPT * B_ * D_ * I_;             // [B*D*I]
    float* s1 = s0 + B_ * D_ * I_;                               // [B*D*I]
    float* n2 = s1 + B_ * D_ * I_;                               // [3]

    hipMemsetAsync(n2, 0, 3 * sizeof(float), stream);

    // r = 0: u_hat production + uniform-c (0.1) partial sums
    k_uhat<<<NPT * 4 * D_, 512, 0, stream>>>(x, W, uhat, s_part);
    k_sred<<<(B_ * D_ * I_) / 256, 256, 0, stream>>>(s_part, s0, n2 + 0);
    // r = 1: t = g0*s0
    k_route<<<B_, 1024, 0, stream>>>(uhat, s0, s1, n2, 1, s1);
    // r = 2: t = g0*s0 + g1*s1; raw s2 -> d_out
    k_route<<<B_, 1024, 0, stream>>>(uhat, s0, s1, n2, 2, out);
    // out = g2 * s2 (in place)
    k_out<<<(B_ * D_ * I_) / 256, 256, 0, stream>>>(out, n2 + 2);
}